// Round 1
// baseline (643.179 us; speedup 1.0000x reference)
//
#include <hip/hip_runtime.h>
#include <cstdint>
#include <cstddef>

// Problem constants (from reference)
#define TOKENS 2048
#define IN_F   4096
#define OUT_F  11008
#define W_BIT  4
#define RANK   16
#define QWB    (OUT_F * IN_F / 8)   // 5,636,096 int32 "bytes" per bit-plane

typedef unsigned short ushort_t;
typedef __attribute__((ext_vector_type(8))) short   short8;   // 8 bf16 = 4 VGPRs (MFMA A/B frag)
typedef __attribute__((ext_vector_type(4))) float   floatx4;  // MFMA C/D frag

__device__ __forceinline__ ushort_t f2bf(float f) {
  union { float f; uint32_t u; } c; c.f = f;
  uint32_t r = c.u + 0x7FFFu + ((c.u >> 16) & 1u);  // RNE
  return (ushort_t)(r >> 16);
}

// async global->LDS, 16B per lane; lds pointer must be wave-uniform base (HW adds lane*16)
__device__ __forceinline__ void gl_lds16(const void* g, void* l) {
  __builtin_amdgcn_global_load_lds(
      (const __attribute__((address_space(1))) uint32_t*)g,
      (__attribute__((address_space(3))) uint32_t*)l, 16, 0, 0);
}

// ---------------- phase 0: x fp32 -> bf16 ----------------
// grid = TOKENS*IN_F/1024 blocks of 256; each thread converts one float4.
__global__ __launch_bounds__(256) void k_cvt_x(const float* __restrict__ x,
                                               ushort_t* __restrict__ xb) {
  int idx = blockIdx.x * 256 + threadIdx.x;
  float4 v = ((const float4*)x)[idx];
  ushort4 r;
  r.x = f2bf(v.x); r.y = f2bf(v.y); r.z = f2bf(v.z); r.w = f2bf(v.w);
  ((ushort4*)xb)[idx] = r;
}

// ---------------- phase 1: build w (bf16) ----------------
// w[o,i] = sum_b sign(b,o,i) * sum_k u[b,o,k]*vt[b,k,i]
// Block tile: 128 o x 128 i. 4 waves in 2x2 quadrants of 64x64; each lane owns 8o x 8i.
// u staged transposed (u_t[b][k][oo], padded row 132 to break write conflicts),
// vt staged natural (vt_s[b][k][ii]). Outer-product in registers; sign applied per bit-plane.
__global__ __launch_bounds__(256) void k_build_w(const int* __restrict__ qw,
                                                 const float* __restrict__ u,
                                                 const float* __restrict__ vt,
                                                 ushort_t* __restrict__ w) {
  __shared__ float u_t[4 * 16 * 132];   // ~33.8 KB
  __shared__ float vt_s[4 * 16 * 128];  // 32 KB
  const int tid = threadIdx.x;
  const int ob = blockIdx.x / (IN_F / 128);
  const int ib = blockIdx.x % (IN_F / 128);
  const int o0 = ob * 128, i0 = ib * 128;

  // stage u: global reads fully contiguous; LDS writes transposed (pad 132 -> 2-way max)
  for (int n = 0; n < 32; ++n) {
    int e = n * 256 + tid;               // [0, 8192)
    int b = e >> 11, rem = e & 2047;
    int oo = rem >> 4, k = rem & 15;
    u_t[(b * 16 + k) * 132 + oo] = u[(size_t)(b * OUT_F + o0 + oo) * RANK + k];
  }
  // stage vt: contiguous reads and writes
  for (int n = 0; n < 32; ++n) {
    int e = n * 256 + tid;
    int b = e >> 11, rem = e & 2047;
    int k = rem >> 7, ii = rem & 127;
    vt_s[(b * 16 + k) * 128 + ii] = vt[(size_t)(b * RANK + k) * IN_F + i0 + ii];
  }
  __syncthreads();

  const int lane = tid & 63, wv = tid >> 6;
  const int o_loc = (wv >> 1) * 64 + (lane >> 3) * 8;  // local o of this lane's 8-row strip
  const int i_loc = (wv & 1) * 64 + (lane & 7) * 8;    // local i of this lane's 8-col strip

  float accT[64];
  #pragma unroll
  for (int i = 0; i < 64; ++i) accT[i] = 0.f;

  #pragma unroll
  for (int b = 0; b < 4; ++b) {
    float accB[64];
    #pragma unroll
    for (int i = 0; i < 64; ++i) accB[i] = 0.f;
    #pragma unroll
    for (int k = 0; k < 16; ++k) {
      floatx4 uo0 = *(const floatx4*)&u_t[(b * 16 + k) * 132 + o_loc];
      floatx4 uo1 = *(const floatx4*)&u_t[(b * 16 + k) * 132 + o_loc + 4];
      floatx4 vi0 = *(const floatx4*)&vt_s[(b * 16 + k) * 128 + i_loc];
      floatx4 vi1 = *(const floatx4*)&vt_s[(b * 16 + k) * 128 + i_loc + 4];
      float uo[8] = {uo0.x, uo0.y, uo0.z, uo0.w, uo1.x, uo1.y, uo1.z, uo1.w};
      float vi[8] = {vi0.x, vi0.y, vi0.z, vi0.w, vi1.x, vi1.y, vi1.z, vi1.w};
      #pragma unroll
      for (int oo = 0; oo < 8; ++oo)
        #pragma unroll
        for (int ii = 0; ii < 8; ++ii)
          accB[oo * 8 + ii] += uo[oo] * vi[ii];
    }
    // apply signs: byte m = o*(IN_F/8) + i/8, bit j = i%8; bit=1 -> +1
    const size_t qcol = (size_t)((i0 + i_loc) >> 3);
    #pragma unroll
    for (int oo = 0; oo < 8; ++oo) {
      int qv = qw[(size_t)b * QWB + (size_t)(o0 + o_loc + oo) * (IN_F / 8) + qcol];
      #pragma unroll
      for (int ii = 0; ii < 8; ++ii) {
        float v = accB[oo * 8 + ii];
        accT[oo * 8 + ii] += ((qv >> ii) & 1) ? v : -v;
      }
    }
  }

  #pragma unroll
  for (int oo = 0; oo < 8; ++oo) {
    ushort4 p0, p1;
    p0.x = f2bf(accT[oo * 8 + 0]); p0.y = f2bf(accT[oo * 8 + 1]);
    p0.z = f2bf(accT[oo * 8 + 2]); p0.w = f2bf(accT[oo * 8 + 3]);
    p1.x = f2bf(accT[oo * 8 + 4]); p1.y = f2bf(accT[oo * 8 + 5]);
    p1.z = f2bf(accT[oo * 8 + 6]); p1.w = f2bf(accT[oo * 8 + 7]);
    ushort_t* dst = &w[(size_t)(o0 + o_loc + oo) * IN_F + i0 + i_loc];
    ((ushort4*)dst)[0] = p0;
    ((ushort4*)dst)[1] = p1;
  }
}

// ---------------- phase 2: y = x @ w^T  (bf16 MFMA gemm_bt) ----------------
// M=2048, N=11008, K=4096. BM=BN=128, BK=32. 256 threads = 4 waves (2x2), wave tile 64x64
// = 4x4 frags of 16x16x32. Staging via global_load_lds width 16 (m97 structure).
__global__ __launch_bounds__(256) void k_gemm_bt(const ushort_t* __restrict__ A,  // [2048][4096]
                                                 const ushort_t* __restrict__ B,  // [11008][4096]
                                                 float* __restrict__ C) {         // [2048][11008]
  __shared__ ushort_t As[128 * 32];  // 8 KB
  __shared__ ushort_t Bs[128 * 32];  // 8 KB
  const int tid = threadIdx.x;
  const int bm = blockIdx.x & 15;        // bm fastest: blocks sharing a w-tile run adjacently
  const int bn = blockIdx.x >> 4;
  const int lane = tid & 63, wv = tid >> 6;
  const int wm = (wv >> 1) * 64, wn = (wv & 1) * 64;
  const int l16 = lane & 15, q = lane >> 4;

  floatx4 acc[16];
  #pragma unroll
  for (int i = 0; i < 16; ++i) acc[i] = (floatx4){0.f, 0.f, 0.f, 0.f};

  // staging chunk map: chunk c in [0,512): row=c>>2 (of 128), col=(c&3)*8 (of 32 bf16)
  const int c0 = tid,        row0 = c0 >> 2, col0 = (c0 & 3) << 3;
  const int c1 = 256 + tid,  row1 = c1 >> 2, col1 = (c1 & 3) << 3;
  const int ldsb0 = (tid & 192) * 16;          // wave-uniform LDS byte base, round 0
  const int ldsb1 = (256 + (tid & 192)) * 16;  // round 1
  const size_t ar = (size_t)(bm * 128), br = (size_t)(bn * 128);

  for (int kt = 0; kt < IN_F; kt += 32) {
    gl_lds16(A + (ar + row0) * IN_F + kt + col0, (char*)As + ldsb0);
    gl_lds16(A + (ar + row1) * IN_F + kt + col1, (char*)As + ldsb1);
    gl_lds16(B + (br + row0) * IN_F + kt + col0, (char*)Bs + ldsb0);
    gl_lds16(B + (br + row1) * IN_F + kt + col1, (char*)Bs + ldsb1);
    __syncthreads();

    short8 af[4], bf[4];
    #pragma unroll
    for (int mi = 0; mi < 4; ++mi)
      af[mi] = *(const short8*)&As[(wm + mi * 16 + l16) * 32 + q * 8];
    #pragma unroll
    for (int ni = 0; ni < 4; ++ni)
      bf[ni] = *(const short8*)&Bs[(wn + ni * 16 + l16) * 32 + q * 8];
    #pragma unroll
    for (int mi = 0; mi < 4; ++mi)
      #pragma unroll
      for (int ni = 0; ni < 4; ++ni)
        acc[mi * 4 + ni] =
            __builtin_amdgcn_mfma_f32_16x16x32_bf16(af[mi], bf[ni], acc[mi * 4 + ni], 0, 0, 0);
    __syncthreads();
  }

  // C/D layout: col = lane&15, row = (lane>>4)*4 + reg  [verified m89/m91]
  #pragma unroll
  for (int mi = 0; mi < 4; ++mi) {
    #pragma unroll
    for (int ni = 0; ni < 4; ++ni) {
      #pragma unroll
      for (int v = 0; v < 4; ++v) {
        int r = bm * 128 + wm + mi * 16 + q * 4 + v;
        int c = bn * 128 + wn + ni * 16 + l16;
        C[(size_t)r * OUT_F + c] = acc[mi * 4 + ni][v];
      }
    }
  }
}

extern "C" void kernel_launch(void* const* d_in, const int* in_sizes, int n_in,
                              void* d_out, int out_size, void* d_ws, size_t ws_size,
                              hipStream_t stream) {
  (void)in_sizes; (void)n_in; (void)out_size; (void)ws_size;
  const float* x  = (const float*)d_in[0];
  const int*   qw = (const int*)d_in[1];
  const float* u  = (const float*)d_in[2];
  const float* vt = (const float*)d_in[3];
  float* out = (float*)d_out;

  // workspace layout: [0,16MB) x_bf16; [16MB, 16+90MB) w_bf16
  ushort_t* xb = (ushort_t*)d_ws;
  ushort_t* wb = (ushort_t*)((char*)d_ws + (size_t)TOKENS * IN_F * sizeof(ushort_t));

  k_cvt_x<<<TOKENS * IN_F / 1024, 256, 0, stream>>>(x, xb);
  k_build_w<<<(OUT_F / 128) * (IN_F / 128), 256, 0, stream>>>(qw, u, vt, wb);
  k_gemm_bt<<<16 * (OUT_F / 128), 256, 0, stream>>>(xb, wb, out);
}

// Round 2
// 564.442 us; speedup vs baseline: 1.1395x; 1.1395x over previous
//
#include <hip/hip_runtime.h>
#include <cstdint>
#include <cstddef>

// Problem constants (from reference)
#define TOKENS 2048
#define IN_F   4096
#define OUT_F  11008
#define W_BIT  4
#define RANK   16
#define QWB    (OUT_F * IN_F / 8)   // 5,636,096 int32 "bytes" per bit-plane

typedef unsigned short ushort_t;
typedef __attribute__((ext_vector_type(8))) short   short8;   // 8 bf16 = 4 VGPRs (MFMA A/B frag)
typedef __attribute__((ext_vector_type(4))) float   floatx4;  // MFMA C/D frag

__device__ __forceinline__ ushort_t f2bf(float f) {
  union { float f; uint32_t u; } c; c.f = f;
  uint32_t r = c.u + 0x7FFFu + ((c.u >> 16) & 1u);  // RNE
  return (ushort_t)(r >> 16);
}

// async global->LDS, 16B per lane; lds pointer must be wave-uniform base (HW adds lane*16)
__device__ __forceinline__ void gl_lds16(const void* g, void* l) {
  __builtin_amdgcn_global_load_lds(
      (const __attribute__((address_space(1))) uint32_t*)g,
      (__attribute__((address_space(3))) uint32_t*)l, 16, 0, 0);
}

// ---------------- phase 0a: x fp32 -> bf16 ----------------
__global__ __launch_bounds__(256) void k_cvt_x(const float* __restrict__ x,
                                               ushort_t* __restrict__ xb) {
  int idx = blockIdx.x * 256 + threadIdx.x;
  float4 v = ((const float4*)x)[idx];
  ushort4 r;
  r.x = f2bf(v.x); r.y = f2bf(v.y); r.z = f2bf(v.z); r.w = f2bf(v.w);
  ((ushort4*)xb)[idx] = r;
}

// ---------------- phase 0b: u -> bf16 (same layout), vt -> bf16 transposed ----------------
// ub[b][o][k]  (row = 16 bf16 = 32B, MFMA A-frag readable as 16B halves)
// vtT[b][i][k] (row = 16 bf16 = 32B, MFMA B-frag readable as 16B halves)
#define N_U  (W_BIT * OUT_F * RANK)   // 704512
#define N_VT (W_BIT * RANK * IN_F)    // 262144
__global__ __launch_bounds__(256) void k_prep_uv(const float* __restrict__ u,
                                                 const float* __restrict__ vt,
                                                 ushort_t* __restrict__ ub,
                                                 ushort_t* __restrict__ vtT) {
  int idx = blockIdx.x * 256 + threadIdx.x;
  if (idx < N_U) {
    ub[idx] = f2bf(u[idx]);
  } else {
    int e = idx - N_U;                 // [0, N_VT)
    int b = e >> 16;                   // RANK*IN_F = 65536
    int r = e & 65535;
    int k = r >> 12;                   // IN_F = 4096
    int i = r & 4095;
    vtT[((size_t)b * IN_F + i) * RANK + k] = f2bf(vt[e]);
  }
}

// ---------------- phase 1: build w (bf16) via MFMA, no LDS ----------------
// w[o,i] = sum_b sign(b,o,i) * (U_b @ Vt_b)[o,i]
// Block tile 128o x 128i; 4 waves 2x2, wave tile 64x64 = 4x4 frags of 16x16.
// Per plane: P = U@Vt via mfma_f32_16x16x32_bf16 with K zero-padded 16->32
// (lanes q>=2 carry zero frags). Sign applied per C-fragment element, then
// accumulated across planes; single bf16 store at the end.
__global__ __launch_bounds__(256) void k_build_w(const int* __restrict__ qw,
                                                 const ushort_t* __restrict__ ub,
                                                 const ushort_t* __restrict__ vtT,
                                                 ushort_t* __restrict__ w) {
  const int tid = threadIdx.x;
  const int ob = blockIdx.x / (IN_F / 128);
  const int ib = blockIdx.x % (IN_F / 128);
  const int o0 = ob * 128, i0 = ib * 128;
  const int lane = tid & 63, wv = tid >> 6;
  const int wm = (wv >> 1) * 64, wn = (wv & 1) * 64;
  const int l16 = lane & 15, q = lane >> 4;
  const bool qlo = (q < 2);
  const int koff = (q & 1) * 8;        // valid k-halves for q=0,1; q>=2 zeroed

  floatx4 acc[16];
  #pragma unroll
  for (int i = 0; i < 16; ++i) acc[i] = (floatx4){0.f, 0.f, 0.f, 0.f};

  const int qcolbase = (i0 + wn + l16) >> 3;   // int32 index within a qw row
  const int bit = l16 & 7;
  const short8 zf = (short8)0;

  #pragma unroll
  for (int b = 0; b < W_BIT; ++b) {
    // fragment loads straight from global (tile working set ~32 KB -> L1/L2 hot)
    short8 af[4], bfr[4];
    #pragma unroll
    for (int mi = 0; mi < 4; ++mi) {
      short8 v = *(const short8*)&ub[((size_t)b * OUT_F + o0 + wm + mi * 16 + l16) * RANK + koff];
      af[mi] = qlo ? v : zf;
    }
    #pragma unroll
    for (int ni = 0; ni < 4; ++ni) {
      short8 v = *(const short8*)&vtT[((size_t)b * IN_F + i0 + wn + ni * 16 + l16) * RANK + koff];
      bfr[ni] = qlo ? v : zf;
    }

    #pragma unroll
    for (int mi = 0; mi < 4; ++mi) {
      floatx4 p[4];
      #pragma unroll
      for (int ni = 0; ni < 4; ++ni)
        p[ni] = __builtin_amdgcn_mfma_f32_16x16x32_bf16(
            af[mi], bfr[ni], (floatx4){0.f, 0.f, 0.f, 0.f}, 0, 0, 0);
      // sign + accumulate: C layout col = l16, row = q*4 + v  [verified m89/m91]
      #pragma unroll
      for (int v4 = 0; v4 < 4; ++v4) {
        const int o = o0 + wm + mi * 16 + q * 4 + v4;
        const int* qrow = qw + (size_t)b * QWB + (size_t)o * (IN_F / 8);
        #pragma unroll
        for (int ni = 0; ni < 4; ++ni) {
          int qv = qrow[qcolbase + ni * 2];
          float s = ((qv >> bit) & 1) ? 1.f : -1.f;
          acc[mi * 4 + ni][v4] = fmaf(s, p[ni][v4], acc[mi * 4 + ni][v4]);
        }
      }
    }
  }

  // store: 16 consecutive lanes (l16) write 16 consecutive bf16 -> 32B segments
  #pragma unroll
  for (int mi = 0; mi < 4; ++mi) {
    #pragma unroll
    for (int v4 = 0; v4 < 4; ++v4) {
      const int o = o0 + wm + mi * 16 + q * 4 + v4;
      #pragma unroll
      for (int ni = 0; ni < 4; ++ni)
        w[(size_t)o * IN_F + i0 + wn + ni * 16 + l16] = f2bf(acc[mi * 4 + ni][v4]);
    }
  }
}

// ---------------- phase 2: y = x @ w^T  (bf16 MFMA gemm_bt) ----------------
// M=2048, N=11008, K=4096. BM=BN=128, BK=32. 256 threads = 4 waves (2x2), wave tile 64x64
// = 4x4 frags of 16x16x32. Staging via global_load_lds width 16 (m97 structure).
__global__ __launch_bounds__(256) void k_gemm_bt(const ushort_t* __restrict__ A,  // [2048][4096]
                                                 const ushort_t* __restrict__ B,  // [11008][4096]
                                                 float* __restrict__ C) {         // [2048][11008]
  __shared__ ushort_t As[128 * 32];  // 8 KB
  __shared__ ushort_t Bs[128 * 32];  // 8 KB
  const int tid = threadIdx.x;
  const int bm = blockIdx.x & 15;        // bm fastest: blocks sharing a w-tile run adjacently
  const int bn = blockIdx.x >> 4;
  const int lane = tid & 63, wv = tid >> 6;
  const int wm = (wv >> 1) * 64, wn = (wv & 1) * 64;
  const int l16 = lane & 15, q = lane >> 4;

  floatx4 acc[16];
  #pragma unroll
  for (int i = 0; i < 16; ++i) acc[i] = (floatx4){0.f, 0.f, 0.f, 0.f};

  // staging chunk map: chunk c in [0,512): row=c>>2 (of 128), col=(c&3)*8 (of 32 bf16)
  const int c0 = tid,        row0 = c0 >> 2, col0 = (c0 & 3) << 3;
  const int c1 = 256 + tid,  row1 = c1 >> 2, col1 = (c1 & 3) << 3;
  const int ldsb0 = (tid & 192) * 16;          // wave-uniform LDS byte base, round 0
  const int ldsb1 = (256 + (tid & 192)) * 16;  // round 1
  const size_t ar = (size_t)(bm * 128), br = (size_t)(bn * 128);

  for (int kt = 0; kt < IN_F; kt += 32) {
    gl_lds16(A + (ar + row0) * IN_F + kt + col0, (char*)As + ldsb0);
    gl_lds16(A + (ar + row1) * IN_F + kt + col1, (char*)As + ldsb1);
    gl_lds16(B + (br + row0) * IN_F + kt + col0, (char*)Bs + ldsb0);
    gl_lds16(B + (br + row1) * IN_F + kt + col1, (char*)Bs + ldsb1);
    __syncthreads();

    short8 af[4], bf[4];
    #pragma unroll
    for (int mi = 0; mi < 4; ++mi)
      af[mi] = *(const short8*)&As[(wm + mi * 16 + l16) * 32 + q * 8];
    #pragma unroll
    for (int ni = 0; ni < 4; ++ni)
      bf[ni] = *(const short8*)&Bs[(wn + ni * 16 + l16) * 32 + q * 8];
    #pragma unroll
    for (int mi = 0; mi < 4; ++mi)
      #pragma unroll
      for (int ni = 0; ni < 4; ++ni)
        acc[mi * 4 + ni] =
            __builtin_amdgcn_mfma_f32_16x16x32_bf16(af[mi], bf[ni], acc[mi * 4 + ni], 0, 0, 0);
    __syncthreads();
  }

  // C/D layout: col = lane&15, row = (lane>>4)*4 + reg  [verified m89/m91]
  #pragma unroll
  for (int mi = 0; mi < 4; ++mi) {
    #pragma unroll
    for (int ni = 0; ni < 4; ++ni) {
      #pragma unroll
      for (int v = 0; v < 4; ++v) {
        int r = bm * 128 + wm + mi * 16 + q * 4 + v;
        int c = bn * 128 + wn + ni * 16 + l16;
        C[(size_t)r * OUT_F + c] = acc[mi * 4 + ni][v];
      }
    }
  }
}

extern "C" void kernel_launch(void* const* d_in, const int* in_sizes, int n_in,
                              void* d_out, int out_size, void* d_ws, size_t ws_size,
                              hipStream_t stream) {
  (void)in_sizes; (void)n_in; (void)out_size; (void)ws_size;
  const float* x  = (const float*)d_in[0];
  const int*   qw = (const int*)d_in[1];
  const float* u  = (const float*)d_in[2];
  const float* vt = (const float*)d_in[3];
  float* out = (float*)d_out;

  // workspace layout (bytes):
  //   xb  @ 0         : 2048*4096*2   = 16,777,216
  //   wb  @ 16.0 MB   : 11008*4096*2  = 90,177,536
  //   ub  @ 102.0 MB  : 4*11008*16*2  = 1,409,024
  //   vtT @ 103.3 MB  : 4*4096*16*2   = 524,288     (total ~103.8 MiB)
  char* wsp = (char*)d_ws;
  ushort_t* xb  = (ushort_t*)wsp;
  ushort_t* wb  = (ushort_t*)(wsp + (size_t)TOKENS * IN_F * 2);
  ushort_t* ubf = (ushort_t*)(wsp + (size_t)TOKENS * IN_F * 2 + (size_t)OUT_F * IN_F * 2);
  ushort_t* vtT = (ushort_t*)(wsp + (size_t)TOKENS * IN_F * 2 + (size_t)OUT_F * IN_F * 2 +
                              (size_t)N_U * 2);

  k_cvt_x<<<TOKENS * IN_F / 1024, 256, 0, stream>>>(x, xb);
  k_prep_uv<<<(N_U + N_VT) / 256, 256, 0, stream>>>(u, vt, ubf, vtT);
  k_build_w<<<(OUT_F / 128) * (IN_F / 128), 256, 0, stream>>>(qw, ubf, vtT, wb);
  k_gemm_bt<<<16 * (OUT_F / 128), 256, 0, stream>>>(xb, wb, out);
}

// Round 3
// 526.280 us; speedup vs baseline: 1.2221x; 1.0725x over previous
//
#include <hip/hip_runtime.h>
#include <cstdint>
#include <cstddef>

// Problem constants (from reference)
#define TOKENS 2048
#define IN_F   4096
#define OUT_F  11008
#define W_BIT  4
#define RANK   16
#define QWB    (OUT_F * IN_F / 8)   // 5,636,096 int32 "bytes" per bit-plane

typedef unsigned short ushort_t;
typedef __attribute__((ext_vector_type(8))) short   short8;   // 8 bf16 = 4 VGPRs (MFMA A/B frag)
typedef __attribute__((ext_vector_type(4))) float   floatx4;  // MFMA C/D frag

__device__ __forceinline__ ushort_t f2bf(float f) {
  union { float f; uint32_t u; } c; c.f = f;
  uint32_t r = c.u + 0x7FFFu + ((c.u >> 16) & 1u);  // RNE
  return (ushort_t)(r >> 16);
}

// async global->LDS, 16B per lane; lds pointer must be wave-uniform base (HW adds lane*16)
__device__ __forceinline__ void gl_lds16(const void* g, void* l) {
  __builtin_amdgcn_global_load_lds(
      (const __attribute__((address_space(1))) uint32_t*)g,
      (__attribute__((address_space(3))) uint32_t*)l, 16, 0, 0);
}

// ---------------- phase 0a: x fp32 -> bf16 ----------------
__global__ __launch_bounds__(256) void k_cvt_x(const float* __restrict__ x,
                                               ushort_t* __restrict__ xb) {
  int idx = blockIdx.x * 256 + threadIdx.x;
  float4 v = ((const float4*)x)[idx];
  ushort4 r;
  r.x = f2bf(v.x); r.y = f2bf(v.y); r.z = f2bf(v.z); r.w = f2bf(v.w);
  ((ushort4*)xb)[idx] = r;
}

// ---------------- phase 0b: u -> bf16 (same layout), vt -> bf16 transposed ----------------
#define N_U  (W_BIT * OUT_F * RANK)   // 704512
#define N_VT (W_BIT * RANK * IN_F)    // 262144
__global__ __launch_bounds__(256) void k_prep_uv(const float* __restrict__ u,
                                                 const float* __restrict__ vt,
                                                 ushort_t* __restrict__ ub,
                                                 ushort_t* __restrict__ vtT) {
  int idx = blockIdx.x * 256 + threadIdx.x;
  if (idx < N_U) {
    ub[idx] = f2bf(u[idx]);
  } else {
    int e = idx - N_U;                 // [0, N_VT)
    int b = e >> 16;                   // RANK*IN_F = 65536
    int r = e & 65535;
    int k = r >> 12;                   // IN_F = 4096
    int i = r & 4095;
    vtT[((size_t)b * IN_F + i) * RANK + k] = f2bf(vt[e]);
  }
}

// ---------------- phase 1: build w (bf16): MFMA product + LDS-staged sign apply ----
// w[o,i] = sum_b sign(b,o,i) * (U_b @ Vt_b)[o,i]
// Block tile 128o x 128i; 4 waves 2x2, wave tile 64x64 = 4x4 frags of 16x16.
// qw tile staged to LDS (coalesced int4), row stride 20 ints: compute reads are
// 8-lane broadcasts, 2-way bank aliasing (free per m136), int4 writes 16B-aligned.
__global__ __launch_bounds__(256) void k_build_w(const int* __restrict__ qw,
                                                 const ushort_t* __restrict__ ub,
                                                 const ushort_t* __restrict__ vtT,
                                                 ushort_t* __restrict__ w) {
  __shared__ int qs[W_BIT * 128 * 20];  // 40 KB
  const int tid = threadIdx.x;
  const int ob = blockIdx.x / (IN_F / 128);
  const int ib = blockIdx.x % (IN_F / 128);
  const int o0 = ob * 128, i0 = ib * 128;
  const int lane = tid & 63, wv = tid >> 6;
  const int wm = (wv >> 1) * 64, wn = (wv & 1) * 64;
  const int l16 = lane & 15, q = lane >> 4;
  const bool qlo = (q < 2);
  const int koff = (q & 1) * 8;        // valid k-halves for q=0,1; q>=2 zeroed
  const short8 zf = (short8)0;

  // stage qw tile: 4 planes x 128 rows x 16 ints; 2048 int4 chunks, 8/thread, coalesced
  #pragma unroll
  for (int n = 0; n < 8; ++n) {
    int c = n * 256 + tid;             // [0, 2048)
    int b = c >> 9, rem = c & 511;
    int row = rem >> 2, part = rem & 3;
    int4 v = *(const int4*)(qw + (size_t)b * QWB +
                            (size_t)(o0 + row) * (IN_F / 8) + (i0 >> 3) + part * 4);
    *(int4*)&qs[(b * 128 + row) * 20 + part * 4] = v;
  }

  floatx4 acc[16];
  #pragma unroll
  for (int i = 0; i < 16; ++i) acc[i] = (floatx4){0.f, 0.f, 0.f, 0.f};

  const int qc_base = (wn >> 3) + (l16 >> 3);  // LDS int col for this lane (+ni*2)
  const int bit = l16 & 7;

  __syncthreads();

  #pragma unroll
  for (int b = 0; b < W_BIT; ++b) {
    // fragment loads straight from global (tile working set ~32 KB -> L1/L2 hot)
    short8 af[4], bfr[4];
    #pragma unroll
    for (int mi = 0; mi < 4; ++mi) {
      short8 v = *(const short8*)&ub[((size_t)b * OUT_F + o0 + wm + mi * 16 + l16) * RANK + koff];
      af[mi] = qlo ? v : zf;
    }
    #pragma unroll
    for (int ni = 0; ni < 4; ++ni) {
      short8 v = *(const short8*)&vtT[((size_t)b * IN_F + i0 + wn + ni * 16 + l16) * RANK + koff];
      bfr[ni] = qlo ? v : zf;
    }

    #pragma unroll
    for (int mi = 0; mi < 4; ++mi) {
      floatx4 p[4];
      #pragma unroll
      for (int ni = 0; ni < 4; ++ni)
        p[ni] = __builtin_amdgcn_mfma_f32_16x16x32_bf16(
            af[mi], bfr[ni], (floatx4){0.f, 0.f, 0.f, 0.f}, 0, 0, 0);
      // C layout: col = l16, row = q*4 + v4  [verified m89/m91]
      #pragma unroll
      for (int v4 = 0; v4 < 4; ++v4) {
        const int o_loc = wm + mi * 16 + q * 4 + v4;
        const int* qrow = &qs[(b * 128 + o_loc) * 20];
        #pragma unroll
        for (int ni = 0; ni < 4; ++ni) {
          int qv = qrow[qc_base + ni * 2];
          float pv = p[ni][v4];
          acc[mi * 4 + ni][v4] += ((qv >> bit) & 1) ? pv : -pv;
        }
      }
    }
  }

  // store: 16 consecutive lanes (l16) write 16 consecutive bf16 -> 32B segments
  #pragma unroll
  for (int mi = 0; mi < 4; ++mi) {
    #pragma unroll
    for (int v4 = 0; v4 < 4; ++v4) {
      const int o = o0 + wm + mi * 16 + q * 4 + v4;
      #pragma unroll
      for (int ni = 0; ni < 4; ++ni)
        w[(size_t)o * IN_F + i0 + wn + ni * 16 + l16] = f2bf(acc[mi * 4 + ni][v4]);
    }
  }
}

// ---------------- phase 2: y = x @ w^T  (bf16 MFMA gemm_bt) ----------------
// M=2048, N=11008, K=4096. BM=BN=128, BK=32. 256 threads = 4 waves (2x2), wave tile 64x64
// = 4x4 frags of 16x16x32. Staging via global_load_lds width 16 (m97 structure).
__global__ __launch_bounds__(256) void k_gemm_bt(const ushort_t* __restrict__ A,  // [2048][4096]
                                                 const ushort_t* __restrict__ B,  // [11008][4096]
                                                 float* __restrict__ C) {         // [2048][11008]
  __shared__ ushort_t As[128 * 32];  // 8 KB
  __shared__ ushort_t Bs[128 * 32];  // 8 KB
  const int tid = threadIdx.x;
  const int bm = blockIdx.x & 15;        // bm fastest: blocks sharing a w-tile run adjacently
  const int bn = blockIdx.x >> 4;
  const int lane = tid & 63, wv = tid >> 6;
  const int wm = (wv >> 1) * 64, wn = (wv & 1) * 64;
  const int l16 = lane & 15, q = lane >> 4;

  floatx4 acc[16];
  #pragma unroll
  for (int i = 0; i < 16; ++i) acc[i] = (floatx4){0.f, 0.f, 0.f, 0.f};

  // staging chunk map: chunk c in [0,512): row=c>>2 (of 128), col=(c&3)*8 (of 32 bf16)
  const int c0 = tid,        row0 = c0 >> 2, col0 = (c0 & 3) << 3;
  const int c1 = 256 + tid,  row1 = c1 >> 2, col1 = (c1 & 3) << 3;
  const int ldsb0 = (tid & 192) * 16;          // wave-uniform LDS byte base, round 0
  const int ldsb1 = (256 + (tid & 192)) * 16;  // round 1
  const size_t ar = (size_t)(bm * 128), br = (size_t)(bn * 128);

  for (int kt = 0; kt < IN_F; kt += 32) {
    gl_lds16(A + (ar + row0) * IN_F + kt + col0, (char*)As + ldsb0);
    gl_lds16(A + (ar + row1) * IN_F + kt + col1, (char*)As + ldsb1);
    gl_lds16(B + (br + row0) * IN_F + kt + col0, (char*)Bs + ldsb0);
    gl_lds16(B + (br + row1) * IN_F + kt + col1, (char*)Bs + ldsb1);
    __syncthreads();

    short8 af[4], bf[4];
    #pragma unroll
    for (int mi = 0; mi < 4; ++mi)
      af[mi] = *(const short8*)&As[(wm + mi * 16 + l16) * 32 + q * 8];
    #pragma unroll
    for (int ni = 0; ni < 4; ++ni)
      bf[ni] = *(const short8*)&Bs[(wn + ni * 16 + l16) * 32 + q * 8];
    #pragma unroll
    for (int mi = 0; mi < 4; ++mi)
      #pragma unroll
      for (int ni = 0; ni < 4; ++ni)
        acc[mi * 4 + ni] =
            __builtin_amdgcn_mfma_f32_16x16x32_bf16(af[mi], bf[ni], acc[mi * 4 + ni], 0, 0, 0);
    __syncthreads();
  }

  // C/D layout: col = lane&15, row = (lane>>4)*4 + reg  [verified m89/m91]
  #pragma unroll
  for (int mi = 0; mi < 4; ++mi) {
    #pragma unroll
    for (int ni = 0; ni < 4; ++ni) {
      #pragma unroll
      for (int v = 0; v < 4; ++v) {
        int r = bm * 128 + wm + mi * 16 + q * 4 + v;
        int c = bn * 128 + wn + ni * 16 + l16;
        C[(size_t)r * OUT_F + c] = acc[mi * 4 + ni][v];
      }
    }
  }
}

extern "C" void kernel_launch(void* const* d_in, const int* in_sizes, int n_in,
                              void* d_out, int out_size, void* d_ws, size_t ws_size,
                              hipStream_t stream) {
  (void)in_sizes; (void)n_in; (void)out_size; (void)ws_size;
  const float* x  = (const float*)d_in[0];
  const int*   qw = (const int*)d_in[1];
  const float* u  = (const float*)d_in[2];
  const float* vt = (const float*)d_in[3];
  float* out = (float*)d_out;

  // workspace layout (bytes):
  //   xb  @ 0         : 2048*4096*2   = 16,777,216
  //   wb  @ 16.0 MB   : 11008*4096*2  = 90,177,536
  //   ub  @ 102.0 MB  : 4*11008*16*2  = 1,409,024
  //   vtT @ 103.3 MB  : 4*4096*16*2   = 524,288     (total ~103.8 MiB)
  char* wsp = (char*)d_ws;
  ushort_t* xb  = (ushort_t*)wsp;
  ushort_t* wb  = (ushort_t*)(wsp + (size_t)TOKENS * IN_F * 2);
  ushort_t* ubf = (ushort_t*)(wsp + (size_t)TOKENS * IN_F * 2 + (size_t)OUT_F * IN_F * 2);
  ushort_t* vtT = (ushort_t*)(wsp + (size_t)TOKENS * IN_F * 2 + (size_t)OUT_F * IN_F * 2 +
                              (size_t)N_U * 2);

  k_cvt_x<<<TOKENS * IN_F / 1024, 256, 0, stream>>>(x, xb);
  k_prep_uv<<<(N_U + N_VT) / 256, 256, 0, stream>>>(u, vt, ubf, vtT);
  k_build_w<<<(OUT_F / 128) * (IN_F / 128), 256, 0, stream>>>(qw, ubf, vtT, wb);
  k_gemm_bt<<<16 * (OUT_F / 128), 256, 0, stream>>>(xb, wb, out);
}